// Round 5
// baseline (119.065 us; speedup 1.0000x reference)
//
#include <hip/hip_runtime.h>
#include <hip/hip_bf16.h>

typedef __attribute__((ext_vector_type(8))) short short8;
typedef __attribute__((ext_vector_type(4))) float floatx4;
typedef __attribute__((ext_vector_type(4))) float f32x4;
typedef unsigned short u16;
typedef unsigned int u32;
typedef __attribute__((ext_vector_type(8))) unsigned short ushort8;

#define LSEQ 1024
#define CHD  128
#define QK_SCALE 0.08838834764831845f  // 1/sqrt(128)

static __device__ __forceinline__ u16 f2b(float f) {
  __hip_bfloat16 h = __float2bfloat16(f);
  return *reinterpret_cast<u16*>(&h);
}
static __device__ __forceinline__ u32 pack2(float a, float b) {
  return (u32)f2b(a) | ((u32)f2b(b) << 16);
}
static __device__ __forceinline__ void gl_lds16(const void* g, void* l) {
  __builtin_amdgcn_global_load_lds((__attribute__((address_space(1))) const void*)g,
                                   (__attribute__((address_space(3))) void*)l, 16, 0, 0);
}

// ---- prep both inputs: f32 [bh][128][1024] -> bf16 V-layout + bf16 transposed ----
__global__ __launch_bounds__(256) void k_prep(const float* __restrict__ cin,
                                              const float* __restrict__ ein,
                                              u16* __restrict__ cV, u16* __restrict__ cT,
                                              u16* __restrict__ eV, u16* __restrict__ eT) {
  __shared__ u16 tile[32][72];
  int z = blockIdx.z;
  const float* in = (z < 32) ? cin : ein;
  u16* outV = (z < 32) ? cV : eV;
  u16* outT = (z < 32) ? cT : eT;
  int bh = z & 31, c0 = blockIdx.y * 32, s0 = blockIdx.x * 64;
  int tid = threadIdx.x;
  int cl = tid >> 3, sc = tid & 7;
  size_t off = ((size_t)bh * CHD + c0 + cl) * LSEQ + s0 + sc * 8;
  f32x4 a = *(const f32x4*)(in + off);
  f32x4 b = *(const f32x4*)(in + off + 4);
  ushort8 u;
#pragma unroll
  for (int j = 0; j < 4; ++j) { u[j] = f2b(a[j]); u[j + 4] = f2b(b[j]); }
  *(ushort8*)(outV + off) = u;
  *(ushort8*)&tile[cl][sc * 8] = u;
  __syncthreads();
  int sl = tid >> 2, cc = tid & 3;
  ushort8 v;
#pragma unroll
  for (int j = 0; j < 8; ++j) v[j] = tile[cc * 8 + j][sl];
  *(ushort8*)(outT + ((size_t)bh * LSEQ + s0 + sl) * CHD + c0 + cc * 8) = v;
}

// ---- W conv f32->bf16, plus zero the 4KB stats buffers ----
__global__ __launch_bounds__(256) void k_wcvt(const float* __restrict__ w, u16* __restrict__ wb,
                                              float* __restrict__ zbuf /* chsum||chsq */) {
  int tid = threadIdx.x;
  int base = (blockIdx.x * 256 + tid) * 8;
  f32x4 a = *(const f32x4*)(w + base);
  f32x4 b = *(const f32x4*)(w + base + 4);
  ushort8 u;
#pragma unroll
  for (int j = 0; j < 4; ++j) { u[j] = f2b(a[j]); u[j + 4] = f2b(b[j]); }
  *(ushort8*)(wb + base) = u;
  if (blockIdx.x == 0) {
    f32x4 z; z[0]=0.f; z[1]=0.f; z[2]=0.f; z[3]=0.f;
    *(f32x4*)(zbuf + tid * 4) = z;
  }
}

// ---- fused double flash attention ----
// phase1: O1 = softmax(scale^2 * (cT.eT^T)^T-ish) -> _c tile; phase2: Q=_c tile, K=eT, V=eV.
// eT,cT: bf16 [bh][1024][128]; cV,eV: bf16 [bh][128][1024]; outT: bf16 [bh][1024][128].
// grid(32 bh, 16 tt), 256 thr (4 waves, 16 t each). LDS 72KB -> 2 blocks/CU.
__global__ __launch_bounds__(256) void k_attn(const u16* __restrict__ eT,
                                              const u16* __restrict__ cT,
                                              const u16* __restrict__ cV,
                                              const u16* __restrict__ eV,
                                              u16* __restrict__ outT) {
  __shared__ char ldsbuf[73728];  // K dbuf 2x16KB | V dbuf 2x16KB | P 4x2KB

  int bh = blockIdx.x, tt = blockIdx.y;
  int tid = threadIdx.x;
  int w = tid >> 6, lane = tid & 63;
  int lo = lane & 15, hi = lane >> 4;
  int t0 = tt * 64 + w * 16;

  char* pw = ldsbuf + 65536 + w * 2048 + lo * 128;
  int sw = (lo & 7) << 4;

  auto stageK = [&](int buf, int sb, const char* kTb) {
    char* dst = ldsbuf + buf * 16384;
#pragma unroll
    for (int it = 0; it < 4; ++it) {
      int bb = it * 4096 + tid * 16;
      int row = bb >> 8;
      int cb = (bb & 255) ^ ((row & 7) << 4);
      gl_lds16(kTb + (size_t)(sb * 64 + row) * 256 + cb, dst + bb);
    }
  };
  auto stageV = [&](int buf, int sb, const char* vb) {
    char* dst = ldsbuf + 32768 + buf * 16384;
#pragma unroll
    for (int it = 0; it < 4; ++it) {
      int bb = it * 4096 + tid * 16;
      int row = bb >> 7;
      int cb = (bb & 127) ^ ((row & 7) << 4);
      gl_lds16(vb + (size_t)row * 2048 + sb * 128 + cb, dst + bb);
    }
  };

  short8 bq[4];       // Q fragments (phase1: from eT; phase2: from O1 handoff)
  floatx4 oacc[8];
  float m_r, l_r;

  auto flash = [&](const char* kTb, const char* vb) {
    m_r = -1e30f; l_r = 0.f;
#pragma unroll
    for (int i = 0; i < 8; ++i) { oacc[i][0]=0.f; oacc[i][1]=0.f; oacc[i][2]=0.f; oacc[i][3]=0.f; }
    stageK(0, 0, kTb); stageV(0, 0, vb);
    __syncthreads();
    int cur = 0;
    for (int sb = 0; sb < 16; ++sb) {
      if (sb < 15) { stageK(cur ^ 1, sb + 1, kTb); stageV(cur ^ 1, sb + 1, vb); }
      const char* ldsK = ldsbuf + cur * 16384;
      const char* ldsV = ldsbuf + 32768 + cur * 16384;

      // S^T = K.Q: lane holds S[s rows][t = t0+lo]
      float sa[4][4];
      __builtin_amdgcn_s_setprio(1);
#pragma unroll
      for (int ss = 0; ss < 4; ++ss) {
        floatx4 acc; acc[0]=0.f; acc[1]=0.f; acc[2]=0.f; acc[3]=0.f;
        int row = ss * 16 + lo;
#pragma unroll
        for (int ks = 0; ks < 4; ++ks) {
          int cbyte = (ks * 64 + hi * 16) ^ ((row & 7) << 4);
          short8 a = *(const short8*)(ldsK + row * 256 + cbyte);
          acc = __builtin_amdgcn_mfma_f32_16x16x32_bf16(a, bq[ks], acc, 0, 0, 0);
        }
#pragma unroll
        for (int r = 0; r < 4; ++r) sa[ss][r] = acc[r] * QK_SCALE;
      }
      __builtin_amdgcn_s_setprio(0);

      // online softmax over s for this t
      float bm = sa[0][0];
#pragma unroll
      for (int ss = 0; ss < 4; ++ss)
#pragma unroll
        for (int r = 0; r < 4; ++r) bm = fmaxf(bm, sa[ss][r]);
      bm = fmaxf(bm, __shfl_xor(bm, 16));
      bm = fmaxf(bm, __shfl_xor(bm, 32));
      float mn = fmaxf(m_r, bm);
      float corr = __expf(m_r - mn);
      m_r = mn;
      float rs = 0.f;
#pragma unroll
      for (int ss = 0; ss < 4; ++ss)
#pragma unroll
        for (int r = 0; r < 4; ++r) {
          float p = __expf(sa[ss][r] - mn);
          sa[ss][r] = p;
          rs += p;
        }
      rs += __shfl_xor(rs, 16);
      rs += __shfl_xor(rs, 32);
      l_r = l_r * corr + rs;
#pragma unroll
      for (int i = 0; i < 8; ++i) {
        oacc[i][0] *= corr; oacc[i][1] *= corr; oacc[i][2] *= corr; oacc[i][3] *= corr;
      }

      // P tile (bf16) -> per-wave LDS [t=lo][s], row-swizzled
#pragma unroll
      for (int ss = 0; ss < 4; ++ss)
#pragma unroll
        for (int r2 = 0; r2 < 2; ++r2) {
          int scol = ss * 16 + hi * 4 + r2 * 2;
          *(u32*)(pw + ((scol * 2) ^ sw)) = pack2(sa[ss][r2 * 2], sa[ss][r2 * 2 + 1]);
        }
      asm volatile("" ::: "memory");  // order P write -> P read (same-wave, TBAA hazard)

      // PV: O[c][t] += sum_s V[c][s] P[t][s]
      __builtin_amdgcn_s_setprio(1);
#pragma unroll
      for (int mt = 0; mt < 8; ++mt) {
        int crow = mt * 16 + lo;
        const char* va = ldsV + crow * 128;
        int vsw = (crow & 7) << 4;
#pragma unroll
        for (int k2 = 0; k2 < 2; ++k2) {
          short8 a = *(const short8*)(va + ((k2 * 64 + hi * 16) ^ vsw));
          short8 b = *(const short8*)(pw + ((k2 * 64 + hi * 16) ^ sw));
          oacc[mt] = __builtin_amdgcn_mfma_f32_16x16x32_bf16(a, b, oacc[mt], 0, 0, 0);
        }
      }
      __builtin_amdgcn_s_setprio(0);
      __syncthreads();
      cur ^= 1;
    }
  };

  // ---------------- phase 1: _c tile = attn(e, c, c) ----------------
  const u16* qbase = eT + ((size_t)bh * LSEQ + t0 + lo) * CHD + hi * 8;
#pragma unroll
  for (int ks = 0; ks < 4; ++ks) bq[ks] = *(const short8*)(qbase + ks * 32);

  flash((const char*)(cT + (size_t)bh * LSEQ * CHD),
        (const char*)(cV + (size_t)bh * CHD * LSEQ));

  // handoff: O1 -> per-wave LDS transpose tile -> phase-2 Q fragments (bf16)
  {
    float inv = 1.0f / l_r;
    char* ot = ldsbuf + w * 4096;  // waves own disjoint 4KB in K buf0 (post-barrier safe)
#pragma unroll
    for (int mt = 0; mt < 8; ++mt)
#pragma unroll
      for (int r2 = 0; r2 < 2; ++r2) {
        int cb = (mt * 32 + hi * 8 + r2 * 4) ^ ((lo & 7) << 4);
        *(u32*)(ot + lo * 256 + cb) = pack2(oacc[mt][r2 * 2] * inv, oacc[mt][r2 * 2 + 1] * inv);
      }
    asm volatile("" ::: "memory");  // same-wave write->read ordering
#pragma unroll
    for (int ks = 0; ks < 4; ++ks) {
      int cb = (ks * 64 + hi * 16) ^ ((lo & 7) << 4);
      bq[ks] = *(const short8*)(ot + lo * 256 + cb);
    }
  }
  __syncthreads();  // protect handoff tile before phase-2 staging overwrites buf0

  // ---------------- phase 2: _e tile = attn(_c, e, e) ----------------
  flash((const char*)(eT + (size_t)bh * LSEQ * CHD),
        (const char*)(eV + (size_t)bh * CHD * LSEQ));

  // epilogue: transpose O2 via per-wave LDS tile, coalesced outT rows
  float inv = 1.0f / l_r;
  char* ot = ldsbuf + w * 4096;
#pragma unroll
  for (int mt = 0; mt < 8; ++mt)
#pragma unroll
    for (int r2 = 0; r2 < 2; ++r2) {
      int cb = (mt * 32 + hi * 8 + r2 * 4) ^ ((lo & 7) << 4);
      *(u32*)(ot + lo * 256 + cb) = pack2(oacc[mt][r2 * 2] * inv, oacc[mt][r2 * 2 + 1] * inv);
    }
  asm volatile("" ::: "memory");
  u16* orow = outT + ((size_t)bh * LSEQ + t0 + lo) * CHD;
#pragma unroll
  for (int it = 0; it < 4; ++it) {
    int cb = (it * 64 + hi * 16) ^ ((lo & 7) << 4);
    ushort8 d = *(const ushort8*)(ot + lo * 256 + cb);
    *(ushort8*)(orow + it * 32 + hi * 8) = d;
  }
}

// ---- proj GEMM 512(o) x 8192(b*l) x 512(c): 128x128 tile, BK=64, dbuf 2-phase ----
__global__ __launch_bounds__(256) void k_proj(const u16* __restrict__ Wm,    // bf16 [512][512]
                                              const u16* __restrict__ eT,    // bf16 [32][1024][128]
                                              const float* __restrict__ bias,
                                              float* __restrict__ x,         // f32 [8][512][1024]
                                              float* __restrict__ chsum,
                                              float* __restrict__ chsq) {
  __shared__ char lds[65536];  // A dbuf 2x16KB | B dbuf 2x16KB
  int lt = blockIdx.x, ot = blockIdx.y;
  int b = lt >> 3;
  int l0b = (lt & 7) * 128;
  int o0 = ot * 128;
  int tid = threadIdx.x, w = tid >> 6, lane = tid & 63, lo = lane & 15, hi = lane >> 4;
  int wm = w >> 1, wn = w & 1;
  const char* Wb = (const char*)Wm;
  const char* eTb = (const char*)eT;

  auto stageA = [&](int buf, int kb) {
    char* dst = lds + buf * 16384;
#pragma unroll
    for (int it = 0; it < 4; ++it) {
      int bb = it * 4096 + tid * 16;
      int row = bb >> 7;
      int cb = (bb & 127) ^ ((row & 7) << 4);
      gl_lds16(Wb + (size_t)(o0 + row) * 1024 + kb * 128 + cb, dst + bb);
    }
  };
  auto stageB = [&](int buf, int kb) {
    char* dst = lds + 32768 + buf * 16384;
    int page = b * 4 + (kb >> 1);
    int choff = (kb & 1) * 128;
#pragma unroll
    for (int it = 0; it < 4; ++it) {
      int bb = it * 4096 + tid * 16;
      int row = bb >> 7;
      int cb = (bb & 127) ^ ((row & 7) << 4);
      gl_lds16(eTb + ((size_t)page * 1024 + l0b + row) * 256 + choff + cb, dst + bb);
    }
  };

  floatx4 acc[4][4];
#pragma unroll
  for (int i = 0; i < 4; ++i)
#pragma unroll
    for (int j = 0; j < 4; ++j) { acc[i][j][0]=0.f; acc[i][j][1]=0.f; acc[i][j][2]=0.f; acc[i][j][3]=0.f; }

  stageA(0, 0); stageB(0, 0);
  __syncthreads();
  int cur = 0;

  for (int kb = 0; kb < 8; ++kb) {
    if (kb < 7) { stageA(cur ^ 1, kb + 1); stageB(cur ^ 1, kb + 1); }
    const char* A = lds + cur * 16384;
    const char* B = lds + 32768 + cur * 16384;
#pragma unroll
    for (int kk = 0; kk < 2; ++kk) {
      short8 af[4], bf[4];
#pragma unroll
      for (int mi = 0; mi < 4; ++mi) {
        int row = wm * 64 + mi * 16 + lo;
        af[mi] = *(const short8*)(A + row * 128 + ((kk * 64 + hi * 16) ^ ((row & 7) << 4)));
      }
#pragma unroll
      for (int ni = 0; ni < 4; ++ni) {
        int row = wn * 64 + ni * 16 + lo;
        bf[ni] = *(const short8*)(B + row * 128 + ((kk * 64 + hi * 16) ^ ((row & 7) << 4)));
      }
      __builtin_amdgcn_s_setprio(1);
#pragma unroll
      for (int mi = 0; mi < 4; ++mi)
#pragma unroll
        for (int ni = 0; ni < 4; ++ni)
          acc[mi][ni] = __builtin_amdgcn_mfma_f32_16x16x32_bf16(af[mi], bf[ni], acc[mi][ni], 0, 0, 0);
      __builtin_amdgcn_s_setprio(0);
    }
    __syncthreads();
    cur ^= 1;
  }

  // epilogue: bias + x write (f32) + per-channel partial stats
#pragma unroll
  for (int mi = 0; mi < 4; ++mi) {
#pragma unroll
    for (int r = 0; r < 4; ++r) {
      int o = o0 + wm * 64 + mi * 16 + hi * 4 + r;
      float bv = bias[o];
      float s = 0.f, q = 0.f;
#pragma unroll
      for (int ni = 0; ni < 4; ++ni) {
        float xv = acc[mi][ni][r] + bv;
        x[((size_t)b * 512 + o) * LSEQ + l0b + wn * 64 + ni * 16 + lo] = xv;
        s += xv; q += xv * xv;
      }
#pragma unroll
      for (int d = 1; d < 16; d <<= 1) { s += __shfl_xor(s, d); q += __shfl_xor(q, d); }
      if (lo == 0) {
        atomicAdd(&chsum[o], s);
        atomicAdd(&chsq[o], q);
      }
    }
  }
}

// ---- BN apply + swish (stats folded in): f32 in, f32 out ----
__global__ __launch_bounds__(256) void k_final(const float* __restrict__ x,
                                               const float* __restrict__ chsum,
                                               const float* __restrict__ chsq,
                                               const float* __restrict__ gamma,
                                               const float* __restrict__ beta,
                                               float* __restrict__ out) {
  int idx = blockIdx.x * 256 + threadIdx.x;
  int base = idx * 4;
  int ch = (base >> 10) & 511;
  const float invn = 1.0f / 8192.0f;
  float mean = chsum[ch] * invn;
  float var = chsq[ch] * invn - mean * mean;
  float rstd = rsqrtf(var + 1e-5f);
  float sc = gamma[ch] * rstd;
  float sh = beta[ch] - mean * sc;
  f32x4 vx = *(const f32x4*)(x + base);
  f32x4 o;
#pragma unroll
  for (int j = 0; j < 4; ++j) {
    float xn = vx[j] * sc + sh;
    float sg = 1.0f / (1.0f + __expf(-xn));
    o[j] = xn * sg;
  }
  *(f32x4*)(out + base) = o;
}

extern "C" void kernel_launch(void* const* d_in, const int* in_sizes, int n_in,
                              void* d_out, int out_size, void* d_ws, size_t ws_size,
                              hipStream_t stream) {
  const float* c     = (const float*)d_in[0];
  const float* e     = (const float*)d_in[1];
  const float* Wf    = (const float*)d_in[2];
  const float* bias  = (const float*)d_in[3];
  const float* gamma = (const float*)d_in[4];
  const float* beta  = (const float*)d_in[5];
  float* outp = (float*)d_out;

  char* ws = (char*)d_ws;
  const size_t TB = (size_t)32 * 1024 * 128 * 2;  // 8.39MB bf16 [bh][*][*] slot
  u16* eT  = (u16*)(ws);                 // S0
  u16* cT  = (u16*)(ws + TB);            // S1
  u16* cV  = (u16*)(ws + 2 * TB);        // S2
  u16* eV  = (u16*)(ws + 3 * TB);        // S3
  u16* xT  = (u16*)(ws + 4 * TB);        // S4: _eT (fused attn output)
  u16* Wbf = (u16*)(ws + 5 * TB);        // 512KB
  float* chsum = (float*)(ws + 5 * TB + (1 << 20));
  float* chsq  = chsum + 512;
  float* x     = (float*)(ws + 6 * TB);  // f32 16.8MB

  dim3 tb(256);

  k_wcvt<<<dim3(128), tb, 0, stream>>>(Wf, Wbf, chsum);   // + zero chsum||chsq
  k_prep<<<dim3(16, 4, 64), tb, 0, stream>>>(c, e, cV, cT, eV, eT);
  k_attn<<<dim3(32, 16), tb, 0, stream>>>(eT, cT, cV, eV, xT);  // _eT fused
  k_proj<<<dim3(64, 4), tb, 0, stream>>>(Wbf, xT, bias, x, chsum, chsq);
  k_final<<<dim3(4096), tb, 0, stream>>>(x, chsum, chsq, gamma, beta, outp);
}

// Round 6
// 111.641 us; speedup vs baseline: 1.0665x; 1.0665x over previous
//
#include <hip/hip_runtime.h>
#include <hip/hip_bf16.h>

typedef __attribute__((ext_vector_type(8))) short short8;
typedef __attribute__((ext_vector_type(4))) float floatx4;
typedef __attribute__((ext_vector_type(4))) float f32x4;
typedef unsigned short u16;
typedef unsigned int u32;
typedef __attribute__((ext_vector_type(2))) unsigned int u32x2;
typedef __attribute__((ext_vector_type(4))) unsigned int u32x4;
typedef __attribute__((ext_vector_type(8))) unsigned short ushort8;

#define LSEQ 1024
#define CHD  128
#define CEXP 0.12751744900425577f   // (1/sqrt(128)) * log2(e)
#define THR_RAW 62.73318f           // 8 / CEXP  (defer-max threshold, raw QK units)

static __device__ __forceinline__ u16 f2b(float f) {
  __hip_bfloat16 h = __float2bfloat16(f);
  return *reinterpret_cast<u16*>(&h);
}
// v_cvt_pk_bf16_f32: dst = {bf16(a) lo, bf16(b) hi}
static __device__ __forceinline__ u32 cvtpk(float a, float b) {
  u32 r;
  asm("v_cvt_pk_bf16_f32 %0, %1, %2" : "=v"(r) : "v"(a), "v"(b));
  return r;
}
static __device__ __forceinline__ float exp2f_fast(float x) {
  float r;
  asm("v_exp_f32 %0, %1" : "=v"(r) : "v"(x));
  return r;
}
static __device__ __forceinline__ void gl_lds16(const void* g, void* l) {
  __builtin_amdgcn_global_load_lds((__attribute__((address_space(1))) const void*)g,
                                   (__attribute__((address_space(3))) void*)l, 16, 0, 0);
}

// ---- prep both inputs: f32 [bh][128][1024] -> bf16 V-layout + bf16 transposed ----
__global__ __launch_bounds__(256) void k_prep(const float* __restrict__ cin,
                                              const float* __restrict__ ein,
                                              u16* __restrict__ cV, u16* __restrict__ cT,
                                              u16* __restrict__ eV, u16* __restrict__ eT) {
  __shared__ u16 tile[32][72];
  int z = blockIdx.z;
  const float* in = (z < 32) ? cin : ein;
  u16* outV = (z < 32) ? cV : eV;
  u16* outT = (z < 32) ? cT : eT;
  int bh = z & 31, c0 = blockIdx.y * 32, s0 = blockIdx.x * 64;
  int tid = threadIdx.x;
  int cl = tid >> 3, sc = tid & 7;
  size_t off = ((size_t)bh * CHD + c0 + cl) * LSEQ + s0 + sc * 8;
  f32x4 a = *(const f32x4*)(in + off);
  f32x4 b = *(const f32x4*)(in + off + 4);
  u32x4 u;
  u[0] = cvtpk(a[0], a[1]); u[1] = cvtpk(a[2], a[3]);
  u[2] = cvtpk(b[0], b[1]); u[3] = cvtpk(b[2], b[3]);
  *(u32x4*)(outV + off) = u;
  *(u32x4*)&tile[cl][sc * 8] = u;
  __syncthreads();
  int sl = tid >> 2, cc = tid & 3;
  ushort8 v;
#pragma unroll
  for (int j = 0; j < 8; ++j) v[j] = tile[cc * 8 + j][sl];
  *(ushort8*)(outT + ((size_t)bh * LSEQ + s0 + sl) * CHD + c0 + cc * 8) = v;
}

// ---- W conv f32->bf16, plus zero the 4KB stats buffers ----
__global__ __launch_bounds__(256) void k_wcvt(const float* __restrict__ w, u16* __restrict__ wb,
                                              float* __restrict__ zbuf /* chsum||chsq */) {
  int tid = threadIdx.x;
  int base = (blockIdx.x * 256 + tid) * 8;
  f32x4 a = *(const f32x4*)(w + base);
  f32x4 b = *(const f32x4*)(w + base + 4);
  u32x4 u;
  u[0] = cvtpk(a[0], a[1]); u[1] = cvtpk(a[2], a[3]);
  u[2] = cvtpk(b[0], b[1]); u[3] = cvtpk(b[2], b[3]);
  *(u32x4*)(wb + base) = u;
  if (blockIdx.x == 0) {
    f32x4 z; z[0]=0.f; z[1]=0.f; z[2]=0.f; z[3]=0.f;
    *(f32x4*)(zbuf + tid * 4) = z;
  }
}

// ---- fused double flash attention ----
// grid(32 bh, 16 tt), 256 thr (4 waves, 16 t each). LDS 72KB -> 2 blocks/CU.
__global__ __launch_bounds__(256) void k_attn(const u16* __restrict__ eT,
                                              const u16* __restrict__ cT,
                                              const u16* __restrict__ cV,
                                              const u16* __restrict__ eV,
                                              u16* __restrict__ outT) {
  __shared__ char ldsbuf[73728];  // K dbuf 2x16KB | V dbuf 2x16KB | P 4x2KB

  int bh = blockIdx.x, tt = blockIdx.y;
  int tid = threadIdx.x;
  int w = tid >> 6, lane = tid & 63;
  int lo = lane & 15, hi = lane >> 4;
  int t0 = tt * 64 + w * 16;

  char* pw = ldsbuf + 65536 + w * 2048 + lo * 128;
  int sw = (lo & 7) << 4;

  auto stageK = [&](int buf, int sb, const char* kTb) {
    char* dst = ldsbuf + buf * 16384;
#pragma unroll
    for (int it = 0; it < 4; ++it) {
      int bb = it * 4096 + tid * 16;
      int row = bb >> 8;
      int cb = (bb & 255) ^ ((row & 7) << 4);
      gl_lds16(kTb + (size_t)(sb * 64 + row) * 256 + cb, dst + bb);
    }
  };
  auto stageV = [&](int buf, int sb, const char* vb) {
    char* dst = ldsbuf + 32768 + buf * 16384;
#pragma unroll
    for (int it = 0; it < 4; ++it) {
      int bb = it * 4096 + tid * 16;
      int row = bb >> 7;
      int cb = (bb & 127) ^ ((row & 7) << 4);
      gl_lds16(vb + (size_t)row * 2048 + sb * 128 + cb, dst + bb);
    }
  };

  short8 bq[4];       // Q fragments (phase1: from eT; phase2: from O1 handoff)
  floatx4 oacc[8];
  float m_r, l_r;

  auto flash = [&](const char* kTb, const char* vb) {
    m_r = -1e30f; l_r = 0.f;
#pragma unroll
    for (int i = 0; i < 8; ++i) { oacc[i][0]=0.f; oacc[i][1]=0.f; oacc[i][2]=0.f; oacc[i][3]=0.f; }
    stageK(0, 0, kTb); stageV(0, 0, vb);
    __syncthreads();
    int cur = 0;
    for (int sb = 0; sb < 16; ++sb) {
      if (sb < 15) { stageK(cur ^ 1, sb + 1, kTb); stageV(cur ^ 1, sb + 1, vb); }
      const char* ldsK = ldsbuf + cur * 16384;
      const char* ldsV = ldsbuf + 32768 + cur * 16384;

      // S^T = K.Q (raw, scale folded into exp2): lane holds S[s rows][t = t0+lo]
      float sa[4][4];
      __builtin_amdgcn_s_setprio(1);
#pragma unroll
      for (int ss = 0; ss < 4; ++ss) {
        floatx4 acc; acc[0]=0.f; acc[1]=0.f; acc[2]=0.f; acc[3]=0.f;
        int row = ss * 16 + lo;
#pragma unroll
        for (int ks = 0; ks < 4; ++ks) {
          int cbyte = (ks * 64 + hi * 16) ^ ((row & 7) << 4);
          short8 a = *(const short8*)(ldsK + row * 256 + cbyte);
          acc = __builtin_amdgcn_mfma_f32_16x16x32_bf16(a, bq[ks], acc, 0, 0, 0);
        }
#pragma unroll
        for (int r = 0; r < 4; ++r) sa[ss][r] = acc[r];
      }
      __builtin_amdgcn_s_setprio(0);

      // block max (max3 tree) + cross-hi reduce
      float x0 = fmaxf(fmaxf(sa[0][0], sa[0][1]), sa[0][2]);
      float x1 = fmaxf(fmaxf(sa[0][3], sa[1][0]), sa[1][1]);
      float x2 = fmaxf(fmaxf(sa[1][2], sa[1][3]), sa[2][0]);
      float x3 = fmaxf(fmaxf(sa[2][1], sa[2][2]), sa[2][3]);
      float x4 = fmaxf(fmaxf(sa[3][0], sa[3][1]), sa[3][2]);
      float bm = fmaxf(fmaxf(fmaxf(x0, x1), fmaxf(x2, x3)), fmaxf(x4, sa[3][3]));
      bm = fmaxf(bm, __shfl_xor(bm, 16));
      bm = fmaxf(bm, __shfl_xor(bm, 32));

      // defer-max: only rescale when the block max meaningfully exceeds m_r
      bool stay = __all(bm - m_r <= THR_RAW);
      if (!stay) {
        float mn = fmaxf(m_r, bm);
        float corr = exp2f_fast((m_r - mn) * CEXP);
        m_r = mn;
        l_r *= corr;
#pragma unroll
        for (int i = 0; i < 8; ++i) {
          oacc[i][0] *= corr; oacc[i][1] *= corr; oacc[i][2] *= corr; oacc[i][3] *= corr;
        }
      }
      float mnC = m_r * CEXP;

      float rs = 0.f;
#pragma unroll
      for (int ss = 0; ss < 4; ++ss)
#pragma unroll
        for (int r = 0; r < 4; ++r) {
          float p = exp2f_fast(__builtin_fmaf(sa[ss][r], CEXP, -mnC));
          sa[ss][r] = p;
          rs += p;
        }
      rs += __shfl_xor(rs, 16);
      rs += __shfl_xor(rs, 32);
      l_r += rs;

      // P tile (bf16) -> per-wave LDS [t=lo][s], row-swizzled; b64 writes
#pragma unroll
      for (int ss = 0; ss < 4; ++ss) {
        u32x2 pk;
        pk[0] = cvtpk(sa[ss][0], sa[ss][1]);
        pk[1] = cvtpk(sa[ss][2], sa[ss][3]);
        *(u32x2*)(pw + ((ss * 32 + hi * 8) ^ sw)) = pk;
      }
      asm volatile("" ::: "memory");  // order P write -> P read (same-wave, TBAA hazard)

      // PV: O[c][t] += sum_s V[c][s] P[t][s]; P B-frags hoisted (2 distinct)
      short8 bp0 = *(const short8*)(pw + ((hi * 16) ^ sw));
      short8 bp1 = *(const short8*)(pw + ((64 + hi * 16) ^ sw));
      __builtin_amdgcn_s_setprio(1);
#pragma unroll
      for (int mt = 0; mt < 8; ++mt) {
        int crow = mt * 16 + lo;
        const char* va = ldsV + crow * 128;
        int vsw = (crow & 7) << 4;
        short8 a0 = *(const short8*)(va + ((hi * 16) ^ vsw));
        short8 a1 = *(const short8*)(va + ((64 + hi * 16) ^ vsw));
        oacc[mt] = __builtin_amdgcn_mfma_f32_16x16x32_bf16(a0, bp0, oacc[mt], 0, 0, 0);
        oacc[mt] = __builtin_amdgcn_mfma_f32_16x16x32_bf16(a1, bp1, oacc[mt], 0, 0, 0);
      }
      __builtin_amdgcn_s_setprio(0);
      __syncthreads();
      cur ^= 1;
    }
  };

  // ---------------- phase 1: _c tile = attn(e, c, c) ----------------
  const u16* qbase = eT + ((size_t)bh * LSEQ + t0 + lo) * CHD + hi * 8;
#pragma unroll
  for (int ks = 0; ks < 4; ++ks) bq[ks] = *(const short8*)(qbase + ks * 32);

  flash((const char*)(cT + (size_t)bh * LSEQ * CHD),
        (const char*)(cV + (size_t)bh * CHD * LSEQ));

  // handoff: O1 -> per-wave LDS transpose tile -> phase-2 Q fragments (bf16)
  {
    float inv = 1.0f / l_r;
    char* ot = ldsbuf + w * 4096;  // waves own disjoint 4KB in K buf0 (post-barrier safe)
#pragma unroll
    for (int mt = 0; mt < 8; ++mt) {
      u32x2 pk;
      pk[0] = cvtpk(oacc[mt][0] * inv, oacc[mt][1] * inv);
      pk[1] = cvtpk(oacc[mt][2] * inv, oacc[mt][3] * inv);
      *(u32x2*)(ot + lo * 256 + ((mt * 32 + hi * 8) ^ ((lo & 7) << 4))) = pk;
    }
    asm volatile("" ::: "memory");  // same-wave write->read ordering
#pragma unroll
    for (int ks = 0; ks < 4; ++ks) {
      int cb = (ks * 64 + hi * 16) ^ ((lo & 7) << 4);
      bq[ks] = *(const short8*)(ot + lo * 256 + cb);
    }
  }
  __syncthreads();  // protect handoff tile before phase-2 staging overwrites buf0

  // ---------------- phase 2: _e tile = attn(_c, e, e) ----------------
  flash((const char*)(eT + (size_t)bh * LSEQ * CHD),
        (const char*)(eV + (size_t)bh * CHD * LSEQ));

  // epilogue: transpose O2 via per-wave LDS tile, coalesced outT rows
  float inv = 1.0f / l_r;
  char* ot = ldsbuf + w * 4096;
#pragma unroll
  for (int mt = 0; mt < 8; ++mt) {
    u32x2 pk;
    pk[0] = cvtpk(oacc[mt][0] * inv, oacc[mt][1] * inv);
    pk[1] = cvtpk(oacc[mt][2] * inv, oacc[mt][3] * inv);
    *(u32x2*)(ot + lo * 256 + ((mt * 32 + hi * 8) ^ ((lo & 7) << 4))) = pk;
  }
  asm volatile("" ::: "memory");
  u16* orow = outT + ((size_t)bh * LSEQ + t0 + lo) * CHD;
#pragma unroll
  for (int it = 0; it < 4; ++it) {
    int cb = (it * 64 + hi * 16) ^ ((lo & 7) << 4);
    ushort8 d = *(const ushort8*)(ot + lo * 256 + cb);
    *(ushort8*)(orow + it * 32 + hi * 8) = d;
  }
}

// ---- proj GEMM 512(o) x 8192(b*l) x 512(c): 128x128 tile, BK=64, dbuf 2-phase ----
// x output now bf16; stats in f32 from accumulators.
__global__ __launch_bounds__(256) void k_proj(const u16* __restrict__ Wm,    // bf16 [512][512]
                                              const u16* __restrict__ eT,    // bf16 [32][1024][128]
                                              const float* __restrict__ bias,
                                              u16* __restrict__ x,           // bf16 [8][512][1024]
                                              float* __restrict__ chsum,
                                              float* __restrict__ chsq) {
  __shared__ char lds[65536];  // A dbuf 2x16KB | B dbuf 2x16KB
  int lt = blockIdx.x, ot = blockIdx.y;
  int b = lt >> 3;
  int l0b = (lt & 7) * 128;
  int o0 = ot * 128;
  int tid = threadIdx.x, w = tid >> 6, lane = tid & 63, lo = lane & 15, hi = lane >> 4;
  int wm = w >> 1, wn = w & 1;
  const char* Wb = (const char*)Wm;
  const char* eTb = (const char*)eT;

  auto stageA = [&](int buf, int kb) {
    char* dst = lds + buf * 16384;
#pragma unroll
    for (int it = 0; it < 4; ++it) {
      int bb = it * 4096 + tid * 16;
      int row = bb >> 7;
      int cb = (bb & 127) ^ ((row & 7) << 4);
      gl_lds16(Wb + (size_t)(o0 + row) * 1024 + kb * 128 + cb, dst + bb);
    }
  };
  auto stageB = [&](int buf, int kb) {
    char* dst = lds + 32768 + buf * 16384;
    int page = b * 4 + (kb >> 1);
    int choff = (kb & 1) * 128;
#pragma unroll
    for (int it = 0; it < 4; ++it) {
      int bb = it * 4096 + tid * 16;
      int row = bb >> 7;
      int cb = (bb & 127) ^ ((row & 7) << 4);
      gl_lds16(eTb + ((size_t)page * 1024 + l0b + row) * 256 + choff + cb, dst + bb);
    }
  };

  floatx4 acc[4][4];
#pragma unroll
  for (int i = 0; i < 4; ++i)
#pragma unroll
    for (int j = 0; j < 4; ++j) { acc[i][j][0]=0.f; acc[i][j][1]=0.f; acc[i][j][2]=0.f; acc[i][j][3]=0.f; }

  stageA(0, 0); stageB(0, 0);
  __syncthreads();
  int cur = 0;

  for (int kb = 0; kb < 8; ++kb) {
    if (kb < 7) { stageA(cur ^ 1, kb + 1); stageB(cur ^ 1, kb + 1); }
    const char* A = lds + cur * 16384;
    const char* B = lds + 32768 + cur * 16384;
#pragma unroll
    for (int kk = 0; kk < 2; ++kk) {
      short8 af[4], bf[4];
#pragma unroll
      for (int mi = 0; mi < 4; ++mi) {
        int row = wm * 64 + mi * 16 + lo;
        af[mi] = *(const short8*)(A + row * 128 + ((kk * 64 + hi * 16) ^ ((row & 7) << 4)));
      }
#pragma unroll
      for (int ni = 0; ni < 4; ++ni) {
        int row = wn * 64 + ni * 16 + lo;
        bf[ni] = *(const short8*)(B + row * 128 + ((kk * 64 + hi * 16) ^ ((row & 7) << 4)));
      }
      __builtin_amdgcn_s_setprio(1);
#pragma unroll
      for (int mi = 0; mi < 4; ++mi)
#pragma unroll
        for (int ni = 0; ni < 4; ++ni)
          acc[mi][ni] = __builtin_amdgcn_mfma_f32_16x16x32_bf16(af[mi], bf[ni], acc[mi][ni], 0, 0, 0);
      __builtin_amdgcn_s_setprio(0);
    }
    __syncthreads();
    cur ^= 1;
  }

  // epilogue: bias + x write (bf16) + per-channel partial stats (f32)
#pragma unroll
  for (int mi = 0; mi < 4; ++mi) {
#pragma unroll
    for (int r = 0; r < 4; ++r) {
      int o = o0 + wm * 64 + mi * 16 + hi * 4 + r;
      float bv = bias[o];
      float s = 0.f, q = 0.f;
#pragma unroll
      for (int ni = 0; ni < 4; ++ni) {
        float xv = acc[mi][ni][r] + bv;
        x[((size_t)b * 512 + o) * LSEQ + l0b + wn * 64 + ni * 16 + lo] = f2b(xv);
        s += xv; q += xv * xv;
      }
#pragma unroll
      for (int d = 1; d < 16; d <<= 1) { s += __shfl_xor(s, d); q += __shfl_xor(q, d); }
      if (lo == 0) {
        atomicAdd(&chsum[o], s);
        atomicAdd(&chsq[o], q);
      }
    }
  }
}

// ---- BN apply + swish (stats folded in): bf16 x in, f32 out ----
__global__ __launch_bounds__(256) void k_final(const u16* __restrict__ x,
                                               const float* __restrict__ chsum,
                                               const float* __restrict__ chsq,
                                               const float* __restrict__ gamma,
                                               const float* __restrict__ beta,
                                               float* __restrict__ out) {
  int idx = blockIdx.x * 256 + threadIdx.x;
  int base = idx * 8;
  int ch = (base >> 10) & 511;
  const float invn = 1.0f / 8192.0f;
  float mean = chsum[ch] * invn;
  float var = chsq[ch] * invn - mean * mean;
  float rstd = rsqrtf(var + 1e-5f);
  float sc = gamma[ch] * rstd;
  float sh = beta[ch] - mean * sc;
  ushort8 vx = *(const ushort8*)(x + base);
  f32x4 o0, o1;
#pragma unroll
  for (int j = 0; j < 8; ++j) {
    union { u32 i; float f; } cv; cv.i = ((u32)vx[j]) << 16;
    float xn = cv.f * sc + sh;
    float sg = 1.0f / (1.0f + __expf(-xn));
    float r = xn * sg;
    if (j < 4) o0[j] = r; else o1[j - 4] = r;
  }
  *(f32x4*)(out + base) = o0;
  *(f32x4*)(out + base + 4) = o1;
}

extern "C" void kernel_launch(void* const* d_in, const int* in_sizes, int n_in,
                              void* d_out, int out_size, void* d_ws, size_t ws_size,
                              hipStream_t stream) {
  const float* c     = (const float*)d_in[0];
  const float* e     = (const float*)d_in[1];
  const float* Wf    = (const float*)d_in[2];
  const float* bias  = (const float*)d_in[3];
  const float* gamma = (const float*)d_in[4];
  const float* beta  = (const float*)d_in[5];
  float* outp = (float*)d_out;

  char* ws = (char*)d_ws;
  const size_t TB = (size_t)32 * 1024 * 128 * 2;  // 8.39MB bf16 [bh][*][*] slot
  u16* eT  = (u16*)(ws);                 // S0
  u16* cT  = (u16*)(ws + TB);            // S1
  u16* cV  = (u16*)(ws + 2 * TB);        // S2
  u16* eV  = (u16*)(ws + 3 * TB);        // S3
  u16* xT  = (u16*)(ws + 4 * TB);        // S4: _eT (fused attn output)
  u16* Wbf = (u16*)(ws + 5 * TB);        // 512KB
  float* chsum = (float*)(ws + 5 * TB + (1 << 20));
  float* chsq  = chsum + 512;
  u16* x   = (u16*)(ws + 6 * TB);        // bf16 8.4MB

  dim3 tb(256);

  k_wcvt<<<dim3(128), tb, 0, stream>>>(Wf, Wbf, chsum);   // + zero chsum||chsq
  k_prep<<<dim3(16, 4, 64), tb, 0, stream>>>(c, e, cV, cT, eV, eT);
  k_attn<<<dim3(32, 16), tb, 0, stream>>>(eT, cT, cV, eV, xT);  // _eT fused
  k_proj<<<dim3(64, 4), tb, 0, stream>>>(Wbf, xT, bias, x, chsum, chsq);
  k_final<<<dim3(2048), tb, 0, stream>>>(x, chsum, chsq, gamma, beta, outp);
}

// Round 7
// 109.245 us; speedup vs baseline: 1.0899x; 1.0219x over previous
//
#include <hip/hip_runtime.h>
#include <hip/hip_bf16.h>

typedef __attribute__((ext_vector_type(8))) short short8;
typedef __attribute__((ext_vector_type(4))) float floatx4;
typedef __attribute__((ext_vector_type(4))) float f32x4;
typedef unsigned short u16;
typedef unsigned int u32;
typedef __attribute__((ext_vector_type(2))) unsigned int u32x2;
typedef __attribute__((ext_vector_type(4))) unsigned int u32x4;
typedef __attribute__((ext_vector_type(8))) unsigned short ushort8;

#define LSEQ 1024
#define CHD  128
#define CEXP 0.12751744900425577f   // (1/sqrt(128)) * log2(e)
#define THR_RAW 62.73318f           // 8 / CEXP  (defer-max threshold, raw QK units)

static __device__ __forceinline__ u16 f2b(float f) {
  __hip_bfloat16 h = __float2bfloat16(f);
  return *reinterpret_cast<u16*>(&h);
}
static __device__ __forceinline__ u32 cvtpk(float a, float b) {
  u32 r;
  asm("v_cvt_pk_bf16_f32 %0, %1, %2" : "=v"(r) : "v"(a), "v"(b));
  return r;
}
static __device__ __forceinline__ float exp2f_fast(float x) {
  float r;
  asm("v_exp_f32 %0, %1" : "=v"(r) : "v"(x));
  return r;
}
static __device__ __forceinline__ void gl_lds16(const void* g, void* l) {
  __builtin_amdgcn_global_load_lds((__attribute__((address_space(1))) const void*)g,
                                   (__attribute__((address_space(3))) void*)l, 16, 0, 0);
}

// ---- prep both inputs (z<64) + W convert (z=64,65) + stats zero ----
__global__ __launch_bounds__(256) void k_prep(const float* __restrict__ cin,
                                              const float* __restrict__ ein,
                                              const float* __restrict__ Wf,
                                              u16* __restrict__ cV, u16* __restrict__ cT,
                                              u16* __restrict__ eV, u16* __restrict__ eT,
                                              u16* __restrict__ wb, float* __restrict__ zbuf) {
  __shared__ u16 tile[32][72];
  int z = blockIdx.z;
  int tid = threadIdx.x;
  if (z >= 64) {  // W f32->bf16 (128 virtual blocks) + zero chsum||chsq
    int wblk = (z - 64) * 64 + blockIdx.y * 16 + blockIdx.x;
    int base = (wblk * 256 + tid) * 8;
    f32x4 a = *(const f32x4*)(Wf + base);
    f32x4 b = *(const f32x4*)(Wf + base + 4);
    u32x4 u;
    u[0] = cvtpk(a[0], a[1]); u[1] = cvtpk(a[2], a[3]);
    u[2] = cvtpk(b[0], b[1]); u[3] = cvtpk(b[2], b[3]);
    *(u32x4*)(wb + base) = u;
    if (wblk == 0) {
      f32x4 zz; zz[0]=0.f; zz[1]=0.f; zz[2]=0.f; zz[3]=0.f;
      *(f32x4*)(zbuf + tid * 4) = zz;
    }
    return;
  }
  const float* in = (z < 32) ? cin : ein;
  u16* outV = (z < 32) ? cV : eV;
  u16* outT = (z < 32) ? cT : eT;
  int bh = z & 31, c0 = blockIdx.y * 32, s0 = blockIdx.x * 64;
  int cl = tid >> 3, sc = tid & 7;
  size_t off = ((size_t)bh * CHD + c0 + cl) * LSEQ + s0 + sc * 8;
  f32x4 a = *(const f32x4*)(in + off);
  f32x4 b = *(const f32x4*)(in + off + 4);
  u32x4 u;
  u[0] = cvtpk(a[0], a[1]); u[1] = cvtpk(a[2], a[3]);
  u[2] = cvtpk(b[0], b[1]); u[3] = cvtpk(b[2], b[3]);
  *(u32x4*)(outV + off) = u;
  *(u32x4*)&tile[cl][sc * 8] = u;
  __syncthreads();
  int sl = tid >> 2, cc = tid & 3;
  ushort8 v;
#pragma unroll
  for (int j = 0; j < 8; ++j) v[j] = tile[cc * 8 + j][sl];
  *(ushort8*)(outT + ((size_t)bh * LSEQ + s0 + sl) * CHD + c0 + cc * 8) = v;
}

// ---- fused double flash attention, counted-vmcnt 2-barrier pipeline ----
// grid(32 bh, 16 tt), 256 thr (4 waves, 16 t each). LDS 72KB -> 2 blocks/CU.
__global__ __launch_bounds__(256) void k_attn(const u16* __restrict__ eT,
                                              const u16* __restrict__ cT,
                                              const u16* __restrict__ cV,
                                              const u16* __restrict__ eV,
                                              u16* __restrict__ outT) {
  __shared__ char ldsbuf[73728];  // K dbuf 2x16KB | V dbuf 2x16KB | P 4x2KB

  int bh = blockIdx.x, tt = blockIdx.y;
  int tid = threadIdx.x;
  int w = tid >> 6, lane = tid & 63;
  int lo = lane & 15, hi = lane >> 4;
  int t0 = tt * 64 + w * 16;

  char* pw = ldsbuf + 65536 + w * 2048 + lo * 128;
  int sw = (lo & 7) << 4;

  auto stageK = [&](int buf, int sb, const char* kTb) {
    char* dst = ldsbuf + buf * 16384;
#pragma unroll
    for (int it = 0; it < 4; ++it) {
      int bb = it * 4096 + tid * 16;
      int row = bb >> 8;
      int cb = (bb & 255) ^ ((row & 7) << 4);
      gl_lds16(kTb + (size_t)(sb * 64 + row) * 256 + cb, dst + bb);
    }
  };
  auto stageV = [&](int buf, int sb, const char* vb) {
    char* dst = ldsbuf + 32768 + buf * 16384;
#pragma unroll
    for (int it = 0; it < 4; ++it) {
      int bb = it * 4096 + tid * 16;
      int row = bb >> 7;
      int cb = (bb & 127) ^ ((row & 7) << 4);
      gl_lds16(vb + (size_t)row * 2048 + sb * 128 + cb, dst + bb);
    }
  };

  short8 bq[4];       // Q fragments (phase1: from eT; phase2: from O1 handoff)
  floatx4 oacc[8];
  float m_r, l_r;

  auto flash = [&](const char* kTb, const char* vb) {
    m_r = -1e30f; l_r = 0.f;
#pragma unroll
    for (int i = 0; i < 8; ++i) { oacc[i][0]=0.f; oacc[i][1]=0.f; oacc[i][2]=0.f; oacc[i][3]=0.f; }
    stageK(0, 0, kTb); stageV(0, 0, vb);
    for (int sb = 0; sb < 16; ++sb) {
      int cur = sb & 1;
      // B1: all waves finished compute(sb-1) -> safe to overwrite buf cur^1
      __builtin_amdgcn_s_barrier();
      if (sb < 15) { stageK(cur ^ 1, sb + 1, kTb); stageV(cur ^ 1, sb + 1, vb); }
      // my stage(sb) complete; stage(sb+1)'s 8 loads stay in flight (no drain)
      if (sb < 15) { asm volatile("s_waitcnt vmcnt(8)" ::: "memory"); }
      else         { asm volatile("s_waitcnt vmcnt(0)" ::: "memory"); }
      // B2: everyone's stage(sb) complete
      __builtin_amdgcn_s_barrier();

      const char* ldsK = ldsbuf + cur * 16384;
      const char* ldsV = ldsbuf + 32768 + cur * 16384;

      // S^T = K.Q (raw, scale folded into exp2): lane holds S[s rows][t = t0+lo]
      float sa[4][4];
      __builtin_amdgcn_s_setprio(1);
#pragma unroll
      for (int ss = 0; ss < 4; ++ss) {
        floatx4 acc; acc[0]=0.f; acc[1]=0.f; acc[2]=0.f; acc[3]=0.f;
        int row = ss * 16 + lo;
#pragma unroll
        for (int ks = 0; ks < 4; ++ks) {
          int cbyte = (ks * 64 + hi * 16) ^ ((row & 7) << 4);
          short8 a = *(const short8*)(ldsK + row * 256 + cbyte);
          acc = __builtin_amdgcn_mfma_f32_16x16x32_bf16(a, bq[ks], acc, 0, 0, 0);
        }
#pragma unroll
        for (int r = 0; r < 4; ++r) sa[ss][r] = acc[r];
      }
      __builtin_amdgcn_s_setprio(0);

      // block max (max3 tree) + cross-hi reduce
      float x0 = fmaxf(fmaxf(sa[0][0], sa[0][1]), sa[0][2]);
      float x1 = fmaxf(fmaxf(sa[0][3], sa[1][0]), sa[1][1]);
      float x2 = fmaxf(fmaxf(sa[1][2], sa[1][3]), sa[2][0]);
      float x3 = fmaxf(fmaxf(sa[2][1], sa[2][2]), sa[2][3]);
      float x4 = fmaxf(fmaxf(sa[3][0], sa[3][1]), sa[3][2]);
      float bm = fmaxf(fmaxf(fmaxf(x0, x1), fmaxf(x2, x3)), fmaxf(x4, sa[3][3]));
      bm = fmaxf(bm, __shfl_xor(bm, 16));
      bm = fmaxf(bm, __shfl_xor(bm, 32));

      // defer-max: only rescale when the block max meaningfully exceeds m_r
      bool stay = __all(bm - m_r <= THR_RAW);
      if (!stay) {
        float mn = fmaxf(m_r, bm);
        float corr = exp2f_fast((m_r - mn) * CEXP);
        m_r = mn;
        l_r *= corr;
#pragma unroll
        for (int i = 0; i < 8; ++i) {
          oacc[i][0] *= corr; oacc[i][1] *= corr; oacc[i][2] *= corr; oacc[i][3] *= corr;
        }
      }
      float mnC = m_r * CEXP;

      float rs = 0.f;
#pragma unroll
      for (int ss = 0; ss < 4; ++ss)
#pragma unroll
        for (int r = 0; r < 4; ++r) {
          float p = exp2f_fast(__builtin_fmaf(sa[ss][r], CEXP, -mnC));
          sa[ss][r] = p;
          rs += p;
        }
      rs += __shfl_xor(rs, 16);
      rs += __shfl_xor(rs, 32);
      l_r += rs;

      // P tile (bf16) -> per-wave LDS [t=lo][s], row-swizzled; b64 writes
#pragma unroll
      for (int ss = 0; ss < 4; ++ss) {
        u32x2 pk;
        pk[0] = cvtpk(sa[ss][0], sa[ss][1]);
        pk[1] = cvtpk(sa[ss][2], sa[ss][3]);
        *(u32x2*)(pw + ((ss * 32 + hi * 8) ^ sw)) = pk;
      }
      asm volatile("" ::: "memory");  // order P write -> P read (same-wave, TBAA hazard)

      // PV: O[c][t] += sum_s V[c][s] P[t][s]; P B-frags hoisted (2 distinct)
      short8 bp0 = *(const short8*)(pw + ((hi * 16) ^ sw));
      short8 bp1 = *(const short8*)(pw + ((64 + hi * 16) ^ sw));
      __builtin_amdgcn_s_setprio(1);
#pragma unroll
      for (int mt = 0; mt < 8; ++mt) {
        int crow = mt * 16 + lo;
        const char* va = ldsV + crow * 128;
        int vsw = (crow & 7) << 4;
        short8 a0 = *(const short8*)(va + ((hi * 16) ^ vsw));
        short8 a1 = *(const short8*)(va + ((64 + hi * 16) ^ vsw));
        oacc[mt] = __builtin_amdgcn_mfma_f32_16x16x32_bf16(a0, bp0, oacc[mt], 0, 0, 0);
        oacc[mt] = __builtin_amdgcn_mfma_f32_16x16x32_bf16(a1, bp1, oacc[mt], 0, 0, 0);
      }
      __builtin_amdgcn_s_setprio(0);
      // no trailing barrier: next iteration's B1 provides it (no vmcnt drain!)
    }
  };

  // ---------------- phase 1: _c tile = attn(e, c, c) ----------------
  const u16* qbase = eT + ((size_t)bh * LSEQ + t0 + lo) * CHD + hi * 8;
#pragma unroll
  for (int ks = 0; ks < 4; ++ks) bq[ks] = *(const short8*)(qbase + ks * 32);

  flash((const char*)(cT + (size_t)bh * LSEQ * CHD),
        (const char*)(cV + (size_t)bh * CHD * LSEQ));

  // handoff: O1 -> per-wave LDS transpose tile -> phase-2 Q fragments (bf16)
  {
    float inv = 1.0f / l_r;
    char* ot = ldsbuf + w * 4096;  // waves own disjoint 4KB in K buf0 (post-loop safe)
#pragma unroll
    for (int mt = 0; mt < 8; ++mt) {
      u32x2 pk;
      pk[0] = cvtpk(oacc[mt][0] * inv, oacc[mt][1] * inv);
      pk[1] = cvtpk(oacc[mt][2] * inv, oacc[mt][3] * inv);
      *(u32x2*)(ot + lo * 256 + ((mt * 32 + hi * 8) ^ ((lo & 7) << 4))) = pk;
    }
    asm volatile("" ::: "memory");  // same-wave write->read ordering
#pragma unroll
    for (int ks = 0; ks < 4; ++ks) {
      int cb = (ks * 64 + hi * 16) ^ ((lo & 7) << 4);
      bq[ks] = *(const short8*)(ot + lo * 256 + cb);
    }
  }
  __syncthreads();  // protect handoff tile before phase-2 staging overwrites buf0

  // ---------------- phase 2: _e tile = attn(_c, e, e) ----------------
  flash((const char*)(eT + (size_t)bh * LSEQ * CHD),
        (const char*)(eV + (size_t)bh * CHD * LSEQ));

  // epilogue: transpose O2 via per-wave LDS tile, coalesced outT rows
  float inv = 1.0f / l_r;
  char* ot = ldsbuf + w * 4096;
#pragma unroll
  for (int mt = 0; mt < 8; ++mt) {
    u32x2 pk;
    pk[0] = cvtpk(oacc[mt][0] * inv, oacc[mt][1] * inv);
    pk[1] = cvtpk(oacc[mt][2] * inv, oacc[mt][3] * inv);
    *(u32x2*)(ot + lo * 256 + ((mt * 32 + hi * 8) ^ ((lo & 7) << 4))) = pk;
  }
  asm volatile("" ::: "memory");
  u16* orow = outT + ((size_t)bh * LSEQ + t0 + lo) * CHD;
#pragma unroll
  for (int it = 0; it < 4; ++it) {
    int cb = (it * 64 + hi * 16) ^ ((lo & 7) << 4);
    ushort8 d = *(const ushort8*)(ot + lo * 256 + cb);
    *(ushort8*)(orow + it * 32 + hi * 8) = d;
  }
}

// ---- proj GEMM 512(o) x 8192(b*l) x 512(c): 128x128 tile, BK=64, counted-vmcnt dbuf ----
__global__ __launch_bounds__(256) void k_proj(const u16* __restrict__ Wm,    // bf16 [512][512]
                                              const u16* __restrict__ eT,    // bf16 [32][1024][128]
                                              const float* __restrict__ bias,
                                              u16* __restrict__ x,           // bf16 [8][512][1024]
                                              float* __restrict__ chsum,
                                              float* __restrict__ chsq) {
  __shared__ char lds[65536];  // A dbuf 2x16KB | B dbuf 2x16KB
  int lt = blockIdx.x, ot = blockIdx.y;
  int b = lt >> 3;
  int l0b = (lt & 7) * 128;
  int o0 = ot * 128;
  int tid = threadIdx.x, w = tid >> 6, lane = tid & 63, lo = lane & 15, hi = lane >> 4;
  int wm = w >> 1, wn = w & 1;
  const char* Wb = (const char*)Wm;
  const char* eTb = (const char*)eT;

  auto stageA = [&](int buf, int kb) {
    char* dst = lds + buf * 16384;
#pragma unroll
    for (int it = 0; it < 4; ++it) {
      int bb = it * 4096 + tid * 16;
      int row = bb >> 7;
      int cb = (bb & 127) ^ ((row & 7) << 4);
      gl_lds16(Wb + (size_t)(o0 + row) * 1024 + kb * 128 + cb, dst + bb);
    }
  };
  auto stageB = [&](int buf, int kb) {
    char* dst = lds + 32768 + buf * 16384;
    int page = b * 4 + (kb >> 1);
    int choff = (kb & 1) * 128;
#pragma unroll
    for (int it = 0; it < 4; ++it) {
      int bb = it * 4096 + tid * 16;
      int row = bb >> 7;
      int cb = (bb & 127) ^ ((row & 7) << 4);
      gl_lds16(eTb + ((size_t)page * 1024 + l0b + row) * 256 + choff + cb, dst + bb);
    }
  };

  floatx4 acc[4][4];
#pragma unroll
  for (int i = 0; i < 4; ++i)
#pragma unroll
    for (int j = 0; j < 4; ++j) { acc[i][j][0]=0.f; acc[i][j][1]=0.f; acc[i][j][2]=0.f; acc[i][j][3]=0.f; }

  stageA(0, 0); stageB(0, 0);

  for (int kb = 0; kb < 8; ++kb) {
    int cur = kb & 1;
    __builtin_amdgcn_s_barrier();                  // B1
    if (kb < 7) { stageA(cur ^ 1, kb + 1); stageB(cur ^ 1, kb + 1); }
    if (kb < 7) { asm volatile("s_waitcnt vmcnt(8)" ::: "memory"); }
    else        { asm volatile("s_waitcnt vmcnt(0)" ::: "memory"); }
    __builtin_amdgcn_s_barrier();                  // B2
    const char* A = lds + cur * 16384;
    const char* B = lds + 32768 + cur * 16384;
#pragma unroll
    for (int kk = 0; kk < 2; ++kk) {
      short8 af[4], bf[4];
#pragma unroll
      for (int mi = 0; mi < 4; ++mi) {
        int row = wm * 64 + mi * 16 + lo;
        af[mi] = *(const short8*)(A + row * 128 + ((kk * 64 + hi * 16) ^ ((row & 7) << 4)));
      }
#pragma unroll
      for (int ni = 0; ni < 4; ++ni) {
        int row = wn * 64 + ni * 16 + lo;
        bf[ni] = *(const short8*)(B + row * 128 + ((kk * 64 + hi * 16) ^ ((row & 7) << 4)));
      }
      __builtin_amdgcn_s_setprio(1);
#pragma unroll
      for (int mi = 0; mi < 4; ++mi)
#pragma unroll
        for (int ni = 0; ni < 4; ++ni)
          acc[mi][ni] = __builtin_amdgcn_mfma_f32_16x16x32_bf16(af[mi], bf[ni], acc[mi][ni], 0, 0, 0);
      __builtin_amdgcn_s_setprio(0);
    }
  }

  // epilogue: bias + x write (bf16) + per-channel partial stats (f32)
#pragma unroll
  for (int mi = 0; mi < 4; ++mi) {
#pragma unroll
    for (int r = 0; r < 4; ++r) {
      int o = o0 + wm * 64 + mi * 16 + hi * 4 + r;
      float bv = bias[o];
      float s = 0.f, q = 0.f;
#pragma unroll
      for (int ni = 0; ni < 4; ++ni) {
        float xv = acc[mi][ni][r] + bv;
        x[((size_t)b * 512 + o) * LSEQ + l0b + wn * 64 + ni * 16 + lo] = f2b(xv);
        s += xv; q += xv * xv;
      }
#pragma unroll
      for (int d = 1; d < 16; d <<= 1) { s += __shfl_xor(s, d); q += __shfl_xor(q, d); }
      if (lo == 0) {
        atomicAdd(&chsum[o], s);
        atomicAdd(&chsq[o], q);
      }
    }
  }
}

// ---- BN apply + swish (stats folded in): bf16 x in, f32 out ----
__global__ __launch_bounds__(256) void k_final(const u16* __restrict__ x,
                                               const float* __restrict__ chsum,
                                               const float* __restrict__ chsq,
                                               const float* __restrict__ gamma,
                                               const float* __restrict__ beta,
                                               float* __restrict__ out) {
  int idx = blockIdx.x * 256 + threadIdx.x;
  int base = idx * 8;
  int ch = (base >> 10) & 511;
  const float invn = 1.0f / 8192.0f;
  float mean = chsum[ch] * invn;
  float var = chsq[ch] * invn - mean * mean;
  float rstd = rsqrtf(var + 1e-5f);
  float sc = gamma[ch] * rstd;
  float sh = beta[ch] - mean * sc;
  ushort8 vx = *(const ushort8*)(x + base);
  f32x4 o0, o1;
#pragma unroll
  for (int j = 0; j < 8; ++j) {
    union { u32 i; float f; } cv; cv.i = ((u32)vx[j]) << 16;
    float xn = cv.f * sc + sh;
    float sg = 1.0f / (1.0f + __expf(-xn));
    float r = xn * sg;
    if (j < 4) o0[j] = r; else o1[j - 4] = r;
  }
  *(f32x4*)(out + base) = o0;
  *(f32x4*)(out + base + 4) = o1;
}

extern "C" void kernel_launch(void* const* d_in, const int* in_sizes, int n_in,
                              void* d_out, int out_size, void* d_ws, size_t ws_size,
                              hipStream_t stream) {
  const float* c     = (const float*)d_in[0];
  const float* e     = (const float*)d_in[1];
  const float* Wf    = (const float*)d_in[2];
  const float* bias  = (const float*)d_in[3];
  const float* gamma = (const float*)d_in[4];
  const float* beta  = (const float*)d_in[5];
  float* outp = (float*)d_out;

  char* ws = (char*)d_ws;
  const size_t TB = (size_t)32 * 1024 * 128 * 2;  // 8.39MB bf16 [bh][*][*] slot
  u16* eT  = (u16*)(ws);                 // S0
  u16* cT  = (u16*)(ws + TB);            // S1
  u16* cV  = (u16*)(ws + 2 * TB);        // S2
  u16* eV  = (u16*)(ws + 3 * TB);        // S3
  u16* xT  = (u16*)(ws + 4 * TB);        // S4: _eT (fused attn output)
  u16* Wbf = (u16*)(ws + 5 * TB);        // 512KB
  float* chsum = (float*)(ws + 5 * TB + (1 << 20));
  float* chsq  = chsum + 512;
  u16* x   = (u16*)(ws + 6 * TB);        // bf16 8.4MB

  dim3 tb(256);

  k_prep<<<dim3(16, 4, 66), tb, 0, stream>>>(c, e, Wf, cV, cT, eV, eT, Wbf, chsum);
  k_attn<<<dim3(32, 16), tb, 0, stream>>>(eT, cT, cV, eV, xT);  // _eT fused
  k_proj<<<dim3(64, 4), tb, 0, stream>>>(Wbf, xT, bias, x, chsum, chsq);
  k_final<<<dim3(2048), tb, 0, stream>>>(x, chsum, chsq, gamma, beta, outp);
}